// Round 3
// baseline (130.835 us; speedup 1.0000x reference)
//
#include <hip/hip_runtime.h>

// DepthOffset: for each (b, tap j, oy, ox) find argmin_k |sample(j,k) - center|
// sample(j,k) at (oy + 4*(jr-1) + 2*(kr-1), ox + 4*(jc-1) + 2*(kc-1))
// with TWO-stage zero padding:
//   stage 1 (Sp pad, PH=4): tap pos (oy+4*(jr-1), ox+4*(jc-1)) in-bounds else 0
//   stage 2 (dp pad, SD=2): final pos in-bounds else 0
// masks: taps j=1,7 allow only kc==1; taps j=3,5 allow only kr==1.
// out[b, j,    oy, ox] = (kbest/3 - 1)*2   (off_h)
// out[b, 9+j,  oy, ox] = (kbest%3 - 1)*2   (off_w)
//
// R2: 4 pixels per thread. The stride-2 gather is un-vectorizable for one
// pixel (49 scalar loads), but 4 consecutive pixels share rows: one aligned
// float4 covers 4 needed columns. Per thread: 1 center float4 + 7 rows x 5
// float4 + 18 int4 stores = 54 VMEM per 4 px vs 268 before (5x fewer).
// Rows are consumed in a rolling 3-row window (tap groups jr=0,1,2).
// Border threads (~5%) run the original fully-checked per-pixel path.
// R3 fix: __builtin_nontemporal_store requires a NATIVE vector type, not
// HIP's int4 class -> use ext_vector_type(4) int.

#define BATCH 4
#define IH 480
#define IW 640
#define W4 (IW / 4)

typedef int iv4 __attribute__((ext_vector_type(4)));
typedef float fv4 __attribute__((ext_vector_type(4)));

__global__ __launch_bounds__(256) void depth_offset_kernel(
    const float* __restrict__ d, int* __restrict__ out) {
  int tid = blockIdx.x * blockDim.x + threadIdx.x;
  if (tid >= BATCH * IH * W4) return;
  int ox4 = tid % W4;
  int ox = ox4 * 4;
  int t = tid / W4;
  int oy = t % IH;
  int b = t / IH;

  const float* __restrict__ db = d + (size_t)b * (IH * IW);
  const size_t plane = (size_t)IH * IW;
  int* __restrict__ outb = out + (size_t)b * 18 * plane;
  size_t pix = (size_t)oy * IW + ox;

  // quad-interior: every stage-1/stage-2 check true for all 4 px, and the
  // float4 row window [ox-8, ox+11] is in-bounds.
  bool interior = (oy >= 6) & (oy <= IH - 7) & (ox >= 8) & (ox <= IW - 12);

  if (interior) {
    float cen[4];
    {
      const fv4 c4 = *reinterpret_cast<const fv4*>(db + pix);
      cen[0] = c4.x; cen[1] = c4.y; cen[2] = c4.z; cen[3] = c4.w;
    }
    const float* p = db + (size_t)(oy - 6) * IW + (ox - 8);

    float rows[7][20];
    auto load_row = [&](int i) {
#pragma unroll
      for (int v = 0; v < 5; ++v) {
        const fv4 r =
            *reinterpret_cast<const fv4*>(p + (size_t)(2 * i) * IW + 4 * v);
        rows[i][4 * v + 0] = r.x;
        rows[i][4 * v + 1] = r.y;
        rows[i][4 * v + 2] = r.z;
        rows[i][4 * v + 3] = r.w;
      }
    };

    load_row(0);
    load_row(1);
    load_row(2);

#pragma unroll
    for (int jr = 0; jr < 3; ++jr) {
      if (jr == 1) { load_row(3); load_row(4); }
      if (jr == 2) { load_row(5); load_row(6); }
#pragma unroll
      for (int jc = 0; jc < 3; ++jc) {
        const int j = jr * 3 + jc;
        int bks[4];
#pragma unroll
        for (int q = 0; q < 4; ++q) {
          float best = __builtin_huge_valf();
          int bk = 0;
#pragma unroll
          for (int k = 0; k < 9; ++k) {
            const int kr = k / 3, kc = k % 3;
            bool allowed = true;
            if (j == 1 || j == 7) allowed = (kc == 1);
            if (j == 3 || j == 5) allowed = (kr == 1);
            if (!allowed) continue;  // masked = +inf, never argmin

            // local col of (q, jj=2*jc+kc): q + 2*jj + 2  (in [2, 17])
            float diff =
                fabsf(rows[2 * jr + kr][q + 2 + 2 * (2 * jc + kc)] - cen[q]);
            if (diff < best) {  // strict <: first min wins (jnp.argmin)
              best = diff;
              bk = k;
            }
          }
          bks[q] = bk;
        }
        iv4 oh, ow;
        oh.x = (bks[0] / 3 - 1) * 2; oh.y = (bks[1] / 3 - 1) * 2;
        oh.z = (bks[2] / 3 - 1) * 2; oh.w = (bks[3] / 3 - 1) * 2;
        ow.x = (bks[0] % 3 - 1) * 2; ow.y = (bks[1] % 3 - 1) * 2;
        ow.z = (bks[2] % 3 - 1) * 2; ow.w = (bks[3] % 3 - 1) * 2;
        __builtin_nontemporal_store(
            oh, reinterpret_cast<iv4*>(outb + (size_t)j * plane + pix));
        __builtin_nontemporal_store(
            ow, reinterpret_cast<iv4*>(outb + (size_t)(9 + j) * plane + pix));
      }
    }
  } else {
    // ---------------- border path: original fully-checked code, per px ----
#pragma unroll
    for (int q = 0; q < 4; ++q) {
      const int x0 = ox + q;
      const float center = db[oy * IW + x0];
      float nb[7][7];
#pragma unroll
      for (int i = 0; i < 7; ++i) {
        int y = oy + 2 * i - 6;
        bool yok = ((unsigned)y < (unsigned)IH);
#pragma unroll
        for (int jj = 0; jj < 7; ++jj) {
          int x = x0 + 2 * jj - 6;
          float v = 0.0f;
          if (yok && ((unsigned)x < (unsigned)IW)) v = db[y * IW + x];
          nb[i][jj] = v;
        }
      }

#pragma unroll
      for (int j = 0; j < 9; ++j) {
        const int jr = j / 3, jc = j % 3;
        int Y = oy + 4 * (jr - 1);
        int X = x0 + 4 * (jc - 1);
        bool jok = ((unsigned)Y < (unsigned)IH) && ((unsigned)X < (unsigned)IW);

        float best = __builtin_huge_valf();
        int bk = 0;
#pragma unroll
        for (int k = 0; k < 9; ++k) {
          const int kr = k / 3, kc = k % 3;
          bool allowed = true;
          if (j == 1 || j == 7) allowed = (kc == 1);
          if (j == 3 || j == 5) allowed = (kr == 1);
          if (!allowed) continue;

          float v = jok ? nb[2 * jr + kr][2 * jc + kc] : 0.0f;
          float diff = fabsf(v - center);
          if (diff < best) {
            best = diff;
            bk = k;
          }
        }
        __builtin_nontemporal_store(
            (bk / 3 - 1) * 2, &outb[(size_t)j * plane + pix + q]);
        __builtin_nontemporal_store(
            (bk % 3 - 1) * 2, &outb[(size_t)(9 + j) * plane + pix + q]);
      }
    }
  }
}

extern "C" void kernel_launch(void* const* d_in, const int* in_sizes, int n_in,
                              void* d_out, int out_size, void* d_ws, size_t ws_size,
                              hipStream_t stream) {
  const float* depth = (const float*)d_in[0];
  int* out = (int*)d_out;
  const int total = BATCH * IH * W4;
  const int block = 256;
  const int grid = (total + block - 1) / block;
  depth_offset_kernel<<<grid, block, 0, stream>>>(depth, out);
}

// Round 4
// 105.554 us; speedup vs baseline: 1.2395x; 1.2395x over previous
//
#include <hip/hip_runtime.h>

// DepthOffset: for each (b, tap j, oy, ox) find argmin_k |sample(j,k) - center|
// sample(j,k) at (oy + 4*(jr-1) + 2*(kr-1), ox + 4*(jc-1) + 2*(kc-1))
// with TWO-stage zero padding:
//   stage 1 (Sp pad, PH=4): tap pos (oy+4*(jr-1), ox+4*(jc-1)) in-bounds else 0
//   stage 2 (dp pad, SD=2): final pos in-bounds else 0
// masks: taps j=1,7 allow only kc==1; taps j=3,5 allow only kr==1.
// out[b, j,    oy, ox] = (kbest/3 - 1)*2   (off_h)
// out[b, 9+j,  oy, ox] = (kbest%3 - 1)*2   (off_w)
//
// R4: R3 counters showed 57us, VALUBusy 29%, occupancy 12% -> divergence-
// bound: ~78% of waves straddle the x-border and execute BOTH the interior
// AND the predicated border path. Fix: stage a zero-padded copy of the
// image in d_ws (kernel A), so kernel B is ONE uniform branch-free path:
//   - zeros in the pad region == stage-2 semantics exactly
//   - stage-1 reduces to a per-j scalar fixup: if the tap center is
//     off-image, all allowed candidates tie at |0-center| -> argmin is the
//     FIRST allowed k (jnp.argmin first-wins). kfirst = 1 for j in {1,7},
//     3 for j in {3,5}, else 0. Since tap offsets are +-4 and quads are
//     4 px wide, the x-condition is per-thread-uniform.
// Fallback to the proven R3 kernel if ws_size < pad buffer.

#define BATCH 4
#define IH 480
#define IW 640
#define W4 (IW / 4)

#define PADT 6
#define PADL 6
#define PITCH 656                 // 640+6+6=652, rounded so rows stay 16B-aligned
#define PADH (IH + 2 * PADT)      // 492
#define PPLANE ((size_t)PADH * PITCH)
#define PAD_BYTES ((size_t)BATCH * PPLANE * sizeof(float))  // ~4.93 MB

typedef int iv4 __attribute__((ext_vector_type(4)));
typedef float fv4 __attribute__((ext_vector_type(4)));

// ---------------- Kernel A: zero-padded copy into workspace ----------------
__global__ __launch_bounds__(256) void pad_kernel(
    const float* __restrict__ d, float* __restrict__ pad) {
  const int row4 = PITCH / 4;              // 164
  const int total4 = BATCH * PADH * row4;  // 322,752
  int idx = blockIdx.x * blockDim.x + threadIdx.x;
  if (idx >= total4) return;
  int pxg = idx % row4;
  int t = idx / row4;
  int py = t % PADH;
  int b = t / PADH;
  int y = py - PADT;
  const float* __restrict__ db = d + (size_t)b * (IH * IW);
  fv4 v = {0.0f, 0.0f, 0.0f, 0.0f};
  if ((unsigned)y < (unsigned)IH) {
#pragma unroll
    for (int e = 0; e < 4; ++e) {
      int x = pxg * 4 + e - PADL;
      if ((unsigned)x < (unsigned)IW) v[e] = db[y * IW + x];
    }
  }
  *reinterpret_cast<fv4*>(pad + (size_t)b * PPLANE + (size_t)py * PITCH +
                          pxg * 4) = v;
}

// ---------------- Kernel B: uniform branch-free main kernel ----------------
__global__ __launch_bounds__(256) void depth_offset_main(
    const float* __restrict__ d, const float* __restrict__ pad,
    int* __restrict__ out) {
  int tid = blockIdx.x * blockDim.x + threadIdx.x;
  if (tid >= BATCH * IH * W4) return;
  int ox4 = tid % W4;
  int ox = ox4 * 4;
  int t = tid / W4;
  int oy = t % IH;
  int b = t / IH;

  const float* __restrict__ db = d + (size_t)b * (IH * IW);
  const float* __restrict__ pb = pad + (size_t)b * PPLANE;
  const size_t plane = (size_t)IH * IW;
  int* __restrict__ outb = out + (size_t)b * 18 * plane;
  size_t pix = (size_t)oy * IW + ox;

  float cen[4];
  {
    const fv4 c4 = *reinterpret_cast<const fv4*>(db + pix);
    cen[0] = c4.x; cen[1] = c4.y; cen[2] = c4.z; cen[3] = c4.w;
  }

  // stage-1 badness (tap center off-image). x-side is per-thread-uniform:
  // x0+q-4 < 0  <=> ox == 0 (all 4 quads); x0+q+4 > 639 <=> ox == 636.
  const bool ytop = (oy < 4);
  const bool ybot = (oy > IH - 5);
  const bool xlo = (ox == 0);
  const bool xhi = (ox == IW - 4);

  // padded row window: padded row oy+2i (= image row oy-6+2i), padded col
  // ox (= image col ox-6). Local col of (q, jj): q + 2*jj, jj = 2*jc+kc.
  float rows[7][16];
  auto load_row = [&](int i) {
    const fv4* rp =
        reinterpret_cast<const fv4*>(pb + (size_t)(oy + 2 * i) * PITCH + ox);
#pragma unroll
    for (int v = 0; v < 4; ++v) {
      const fv4 r = rp[v];
      rows[i][4 * v + 0] = r.x;
      rows[i][4 * v + 1] = r.y;
      rows[i][4 * v + 2] = r.z;
      rows[i][4 * v + 3] = r.w;
    }
  };

  load_row(0);
  load_row(1);
  load_row(2);

#pragma unroll
  for (int jr = 0; jr < 3; ++jr) {
    if (jr == 1) { load_row(3); load_row(4); }
    if (jr == 2) { load_row(5); load_row(6); }
#pragma unroll
    for (int jc = 0; jc < 3; ++jc) {
      const int j = jr * 3 + jc;
      const int kf = (j == 1 || j == 7) ? 1 : ((j == 3 || j == 5) ? 3 : 0);
      const bool jbad = ((jr == 0) && ytop) || ((jr == 2) && ybot) ||
                        ((jc == 0) && xlo) || ((jc == 2) && xhi);

      int bks[4];
#pragma unroll
      for (int q = 0; q < 4; ++q) {
        float best = __builtin_huge_valf();
        int bk = 0;
#pragma unroll
        for (int k = 0; k < 9; ++k) {
          const int kr = k / 3, kc = k % 3;
          bool allowed = true;
          if (j == 1 || j == 7) allowed = (kc == 1);
          if (j == 3 || j == 5) allowed = (kr == 1);
          if (!allowed) continue;  // masked = +inf, never argmin

          float diff =
              fabsf(rows[2 * jr + kr][q + 2 * (2 * jc + kc)] - cen[q]);
          if (diff < best) {  // strict <: first min wins (jnp.argmin)
            best = diff;
            bk = k;
          }
        }
        bks[q] = jbad ? kf : bk;  // stage-1 fixup: tie -> first allowed k
      }
      iv4 oh, ow;
      oh.x = (bks[0] / 3 - 1) * 2; oh.y = (bks[1] / 3 - 1) * 2;
      oh.z = (bks[2] / 3 - 1) * 2; oh.w = (bks[3] / 3 - 1) * 2;
      ow.x = (bks[0] % 3 - 1) * 2; ow.y = (bks[1] % 3 - 1) * 2;
      ow.z = (bks[2] % 3 - 1) * 2; ow.w = (bks[3] % 3 - 1) * 2;
      __builtin_nontemporal_store(
          oh, reinterpret_cast<iv4*>(outb + (size_t)j * plane + pix));
      __builtin_nontemporal_store(
          ow, reinterpret_cast<iv4*>(outb + (size_t)(9 + j) * plane + pix));
    }
  }
}

// ---------------- Fallback: proven R3 kernel (if ws too small) -------------
__global__ __launch_bounds__(256) void depth_offset_fallback(
    const float* __restrict__ d, int* __restrict__ out) {
  int tid = blockIdx.x * blockDim.x + threadIdx.x;
  if (tid >= BATCH * IH * W4) return;
  int ox4 = tid % W4;
  int ox = ox4 * 4;
  int t = tid / W4;
  int oy = t % IH;
  int b = t / IH;

  const float* __restrict__ db = d + (size_t)b * (IH * IW);
  const size_t plane = (size_t)IH * IW;
  int* __restrict__ outb = out + (size_t)b * 18 * plane;
  size_t pix = (size_t)oy * IW + ox;

  bool interior = (oy >= 6) & (oy <= IH - 7) & (ox >= 8) & (ox <= IW - 12);

  if (interior) {
    float cen[4];
    {
      const fv4 c4 = *reinterpret_cast<const fv4*>(db + pix);
      cen[0] = c4.x; cen[1] = c4.y; cen[2] = c4.z; cen[3] = c4.w;
    }
    const float* p = db + (size_t)(oy - 6) * IW + (ox - 8);

    float rows[7][20];
    auto load_row = [&](int i) {
#pragma unroll
      for (int v = 0; v < 5; ++v) {
        const fv4 r =
            *reinterpret_cast<const fv4*>(p + (size_t)(2 * i) * IW + 4 * v);
        rows[i][4 * v + 0] = r.x;
        rows[i][4 * v + 1] = r.y;
        rows[i][4 * v + 2] = r.z;
        rows[i][4 * v + 3] = r.w;
      }
    };

    load_row(0);
    load_row(1);
    load_row(2);

#pragma unroll
    for (int jr = 0; jr < 3; ++jr) {
      if (jr == 1) { load_row(3); load_row(4); }
      if (jr == 2) { load_row(5); load_row(6); }
#pragma unroll
      for (int jc = 0; jc < 3; ++jc) {
        const int j = jr * 3 + jc;
        int bks[4];
#pragma unroll
        for (int q = 0; q < 4; ++q) {
          float best = __builtin_huge_valf();
          int bk = 0;
#pragma unroll
          for (int k = 0; k < 9; ++k) {
            const int kr = k / 3, kc = k % 3;
            bool allowed = true;
            if (j == 1 || j == 7) allowed = (kc == 1);
            if (j == 3 || j == 5) allowed = (kr == 1);
            if (!allowed) continue;
            float diff =
                fabsf(rows[2 * jr + kr][q + 2 + 2 * (2 * jc + kc)] - cen[q]);
            if (diff < best) { best = diff; bk = k; }
          }
          bks[q] = bk;
        }
        iv4 oh, ow;
        oh.x = (bks[0] / 3 - 1) * 2; oh.y = (bks[1] / 3 - 1) * 2;
        oh.z = (bks[2] / 3 - 1) * 2; oh.w = (bks[3] / 3 - 1) * 2;
        ow.x = (bks[0] % 3 - 1) * 2; ow.y = (bks[1] % 3 - 1) * 2;
        ow.z = (bks[2] % 3 - 1) * 2; ow.w = (bks[3] % 3 - 1) * 2;
        __builtin_nontemporal_store(
            oh, reinterpret_cast<iv4*>(outb + (size_t)j * plane + pix));
        __builtin_nontemporal_store(
            ow, reinterpret_cast<iv4*>(outb + (size_t)(9 + j) * plane + pix));
      }
    }
  } else {
#pragma unroll
    for (int q = 0; q < 4; ++q) {
      const int x0 = ox + q;
      const float center = db[oy * IW + x0];
      float nb[7][7];
#pragma unroll
      for (int i = 0; i < 7; ++i) {
        int y = oy + 2 * i - 6;
        bool yok = ((unsigned)y < (unsigned)IH);
#pragma unroll
        for (int jj = 0; jj < 7; ++jj) {
          int x = x0 + 2 * jj - 6;
          float v = 0.0f;
          if (yok && ((unsigned)x < (unsigned)IW)) v = db[y * IW + x];
          nb[i][jj] = v;
        }
      }
#pragma unroll
      for (int j = 0; j < 9; ++j) {
        const int jr = j / 3, jc = j % 3;
        int Y = oy + 4 * (jr - 1);
        int X = x0 + 4 * (jc - 1);
        bool jok = ((unsigned)Y < (unsigned)IH) && ((unsigned)X < (unsigned)IW);
        float best = __builtin_huge_valf();
        int bk = 0;
#pragma unroll
        for (int k = 0; k < 9; ++k) {
          const int kr = k / 3, kc = k % 3;
          bool allowed = true;
          if (j == 1 || j == 7) allowed = (kc == 1);
          if (j == 3 || j == 5) allowed = (kr == 1);
          if (!allowed) continue;
          float v = jok ? nb[2 * jr + kr][2 * jc + kc] : 0.0f;
          float diff = fabsf(v - center);
          if (diff < best) { best = diff; bk = k; }
        }
        __builtin_nontemporal_store((bk / 3 - 1) * 2,
                                    &outb[(size_t)j * plane + pix + q]);
        __builtin_nontemporal_store((bk % 3 - 1) * 2,
                                    &outb[(size_t)(9 + j) * plane + pix + q]);
      }
    }
  }
}

extern "C" void kernel_launch(void* const* d_in, const int* in_sizes, int n_in,
                              void* d_out, int out_size, void* d_ws, size_t ws_size,
                              hipStream_t stream) {
  const float* depth = (const float*)d_in[0];
  int* out = (int*)d_out;
  const int block = 256;
  if (d_ws != nullptr && ws_size >= PAD_BYTES) {
    float* pad = (float*)d_ws;
    const int total4 = BATCH * PADH * (PITCH / 4);
    pad_kernel<<<(total4 + block - 1) / block, block, 0, stream>>>(depth, pad);
    const int total = BATCH * IH * W4;
    depth_offset_main<<<(total + block - 1) / block, block, 0, stream>>>(
        depth, pad, out);
  } else {
    const int total = BATCH * IH * W4;
    depth_offset_fallback<<<(total + block - 1) / block, block, 0, stream>>>(
        depth, out);
  }
}